// Round 11
// baseline (141.691 us; speedup 1.0000x reference)
//
#include <hip/hip_runtime.h>
#include <hip/hip_bf16.h>

// Problem constants
#define BB 96    // batch
#define HH 100   // history length
#define NN 128   // candidates (broadcast only)
#define DD 768   // embed dim
#define AA 256   // attention dim

static __device__ __forceinline__ float dot4(float4 a, float4 b) {
  return a.x * b.x + a.y * b.y + a.z * b.z + a.w * b.w;
}

// ---------------------------------------------------------------------------
// D1 k_p1 (1352 blocks): weight-only GEMM generation 1 + neigh partials + c2
//   [0,576)     : 3 GEMMs (A x D out, K = 768), 192 tiles of 32x32 each:
//                 which=0: N  = WK@Wr ; which=1: WA = WQ@Wr ; which=2: WB = WQ@Wl
//   [576,1344)  : neigh partials, 8 h-groups x 96 b (12 h each)
//   [1344,1352) : c2[a] = WQ[a,:]·bl + bQ[a]   (8 blocks x 32 a, wave-split)
// ---------------------------------------------------------------------------
__global__ void __launch_bounds__(256)
k_p1(const float* __restrict__ Wr, const float* __restrict__ Wl,
     const float* __restrict__ WK, const float* __restrict__ WQ,
     const float* __restrict__ bl, const float* __restrict__ bQ,
     const float* __restrict__ hist,
     float* __restrict__ Nm, float* __restrict__ WA, float* __restrict__ WB,
     float* __restrict__ c2, float* __restrict__ neighp) {
  int bid = blockIdx.x, tid = threadIdx.x;
  if (bid < 576) {
    __shared__ float sL[32][33];  // [a][e] tile
    __shared__ float sR[32][33];  // [e][d] tile
    int which = bid / 192, t = bid % 192;
    const float* L = (which == 0) ? WK : WQ;
    const float* R = (which == 2) ? Wl : Wr;
    float* O = (which == 0) ? Nm : (which == 1) ? WA : WB;
    int d0 = (t % 24) * 32, a0 = (t / 24) * 32;
    int tx = tid & 31, ty = tid >> 5;  // 32 x 8
    float acc[4] = {0.f, 0.f, 0.f, 0.f};
    for (int e0 = 0; e0 < DD; e0 += 32) {
#pragma unroll
      for (int k = 0; k < 4; ++k) {
        sL[ty + 8 * k][tx] = L[(size_t)(a0 + ty + 8 * k) * DD + e0 + tx];
        sR[ty + 8 * k][tx] = R[(size_t)(e0 + ty + 8 * k) * DD + d0 + tx];
      }
      __syncthreads();
#pragma unroll 8
      for (int e = 0; e < 32; ++e) {
        float w = sR[e][tx];
#pragma unroll
        for (int k = 0; k < 4; ++k) acc[k] += sL[ty + 8 * k][e] * w;
      }
      __syncthreads();
    }
#pragma unroll
    for (int k = 0; k < 4; ++k)   // O[a,d], coalesced over tx
      O[(size_t)(a0 + ty + 8 * k) * DD + d0 + tx] = acc[k];
  } else if (bid < 1344) {
    int id = bid - 576;
    int b = id % BB, hg = id / BB;  // 8 h-groups of 12
    if (tid < 192) {
      const float* hb = hist + (size_t)b * HH * DD + (size_t)hg * 12 * DD + tid * 4;
      float4 acc = make_float4(0.f, 0.f, 0.f, 0.f);
#pragma unroll
      for (int i = 0; i < 12; ++i) {
        float4 x = *(const float4*)(hb + (size_t)i * DD);
        acc.x += x.x; acc.y += x.y; acc.z += x.z; acc.w += x.w;
      }
      *(float4*)(neighp + ((size_t)hg * BB + b) * DD + tid * 4) = acc;
    }
  } else {
    int a0 = (bid - 1344) * 32;
    int lane = tid & 63, wave = tid >> 6;
    float4 x0 = ((const float4*)bl)[lane];
    float4 x1 = ((const float4*)bl)[lane + 64];
    float4 x2 = ((const float4*)bl)[lane + 128];
    for (int i = 0; i < 8; ++i) {
      int a = a0 + wave * 8 + i;
      const float4* w4 = (const float4*)(WQ + (size_t)a * DD);
      float p = dot4(w4[lane], x0) + dot4(w4[lane + 64], x1) + dot4(w4[lane + 128], x2);
      for (int off = 32; off; off >>= 1) p += __shfl_down(p, off, 64);
      if (lane == 0) c2[a] = p + bQ[a];
    }
  }
}

// ---------------------------------------------------------------------------
// D2 k_p2 (1272 blocks): generation 2 (consumes N, WA, WB, c2, neighp)
//   [0,1152)    : VA[d,e] = sum_a N[a,d]*WA[a,e]  (which=0, 576 tiles) and
//                 VB[d,e] = sum_a N[a,d]*WB[a,e]  (which=1), K = 256
//   [1152,1176) : cv[d] = sum_a N[a,d]*c2[a]   (24 blocks x 32 d)
//   [1176,1272) : neighf[b,:] = (1/96) * sum_g neighp[g][b,:]  (96 blocks)
// ---------------------------------------------------------------------------
__global__ void __launch_bounds__(256)
k_p2(const float* __restrict__ Nm, const float* __restrict__ WA,
     const float* __restrict__ WB, const float* __restrict__ c2,
     const float* __restrict__ neighp,
     float* __restrict__ VA, float* __restrict__ VB, float* __restrict__ cv,
     float* __restrict__ neighf) {
  int bid = blockIdx.x, tid = threadIdx.x;
  if (bid < 1152) {
    __shared__ float sN[32][33];  // [a][d] tile
    __shared__ float sA[32][33];  // [a][e] tile
    int which = bid / 576, t = bid % 576;
    const float* Rm = (which == 0) ? WA : WB;
    float* O = (which == 0) ? VA : VB;
    int e0 = (t % 24) * 32, d0 = (t / 24) * 32;
    int tx = tid & 31, ty = tid >> 5;
    float acc[4] = {0.f, 0.f, 0.f, 0.f};
    for (int a0 = 0; a0 < AA; a0 += 32) {
#pragma unroll
      for (int k = 0; k < 4; ++k) {
        sN[ty + 8 * k][tx] = Nm[(size_t)(a0 + ty + 8 * k) * DD + d0 + tx];
        sA[ty + 8 * k][tx] = Rm[(size_t)(a0 + ty + 8 * k) * DD + e0 + tx];
      }
      __syncthreads();
#pragma unroll 8
      for (int a = 0; a < 32; ++a) {
        float w = sA[a][tx];
#pragma unroll
        for (int k = 0; k < 4; ++k) acc[k] += sN[a][ty + 8 * k] * w;
      }
      __syncthreads();
    }
#pragma unroll
    for (int k = 0; k < 4; ++k)   // VA[d,e], coalesced over tx
      O[(size_t)(d0 + ty + 8 * k) * DD + e0 + tx] = acc[k];
  } else if (bid < 1176) {
    __shared__ float sc2[AA];
    __shared__ float sred[8][32];
    int d0 = (bid - 1152) * 32;
    if (tid < AA) sc2[tid] = c2[tid];
    __syncthreads();
    int dl = tid & 31, g = tid >> 5;  // 8 groups x 32 d
    float acc = 0.f;
#pragma unroll 8
    for (int i = 0; i < 32; ++i) {
      int a = g * 32 + i;
      acc += Nm[(size_t)a * DD + d0 + dl] * sc2[a];
    }
    sred[g][dl] = acc;
    __syncthreads();
    if (tid < 32) {
      float s = 0.f;
#pragma unroll
      for (int gg = 0; gg < 8; ++gg) s += sred[gg][tid];
      cv[d0 + tid] = s;
    }
  } else {
    int b = bid - 1176;
    if (tid < 192) {
      float4 s = make_float4(0.f, 0.f, 0.f, 0.f);
#pragma unroll
      for (int g = 0; g < 8; ++g) {
        float4 x = ((const float4*)(neighp + ((size_t)g * BB + b) * DD))[tid];
        s.x += x.x; s.y += x.y; s.z += x.z; s.w += x.w;
      }
      float4 m = make_float4(s.x * (1.f / 96.f), s.y * (1.f / 96.f),
                             s.z * (1.f / 96.f), s.w * (1.f / 96.f));
      ((float4*)(neighf + (size_t)b * DD))[tid] = m;
    }
  }
}

// ---------------------------------------------------------------------------
// D3 k_v: v[b,d] = (VA[d,:]·hist0[b] + VB[d,:]·neighf[b] + cv[d]) / 16
// dual-stream wave-split-K, 3 b/thread, 32 d/block, grid (24, 32)
// ---------------------------------------------------------------------------
__global__ void k_v(const float* __restrict__ hist, const float* __restrict__ neighf,
                    const float* __restrict__ VA, const float* __restrict__ VB,
                    const float* __restrict__ cv, float* __restrict__ vv) {
  int d0 = blockIdx.x * 32;
  int b0 = blockIdx.y * 3;
  int lane = threadIdx.x & 63, wave = threadIdx.x >> 6;
  float4 xh[3][3], xn[3][3];
#pragma unroll
  for (int bi = 0; bi < 3; ++bi) {
    int b = b0 + bi;
#pragma unroll
    for (int jj = 0; jj < 3; ++jj) {
      int idx = lane + 64 * jj;
      xh[bi][jj] = ((const float4*)(hist + (size_t)b * HH * DD))[idx];  // h=0 row
      xn[bi][jj] = ((const float4*)(neighf + (size_t)b * DD))[idx];
    }
  }
  for (int i = 0; i < 8; ++i) {
    int d = d0 + wave * 8 + i;
    const float4* va4 = (const float4*)(VA + (size_t)d * DD);
    const float4* vb4 = (const float4*)(VB + (size_t)d * DD);
    float pa[3] = {0.f, 0.f, 0.f}, pb[3] = {0.f, 0.f, 0.f};
#pragma unroll
    for (int jj = 0; jj < 3; ++jj) {
      float4 wa = va4[lane + 64 * jj];
      float4 wb = vb4[lane + 64 * jj];
#pragma unroll
      for (int bi = 0; bi < 3; ++bi) {
        pa[bi] += dot4(wa, xh[bi][jj]);
        pb[bi] += dot4(wb, xn[bi][jj]);
      }
    }
#pragma unroll
    for (int bi = 0; bi < 3; ++bi) {
      float pp = pa[bi] + pb[bi];
      for (int off = 32; off; off >>= 1) pp += __shfl_down(pp, off, 64);
      if (lane == 0)
        vv[(size_t)(b0 + bi) * DD + d] = (pp + cv[d]) * (1.f / 16.f);
    }
  }
}

// ---------------------------------------------------------------------------
// D4 k_attn: fused scores -> softmax -> wsum.  grid (96, 3), 256 threads.
// ---------------------------------------------------------------------------
__global__ void __launch_bounds__(256)
k_attn(const float* __restrict__ hist, const float* __restrict__ vv,
       float* __restrict__ wsum) {
  int b = blockIdx.x;
  int es = blockIdx.y;
  int tid = threadIdx.x, lane = tid & 63, wave = tid >> 6;
  __shared__ __align__(16) float sv[DD];
  __shared__ float sal[HH];
  if (tid < 192)
    ((float4*)sv)[tid] = ((const float4*)(vv + (size_t)b * DD))[tid];
  __syncthreads();
  // scores: 4 waves x 25 h
  {
    float4 v0 = ((const float4*)sv)[lane];
    float4 v1 = ((const float4*)sv)[lane + 64];
    float4 v2 = ((const float4*)sv)[lane + 128];
    const float* hb = hist + (size_t)b * HH * DD;
    for (int i = 0; i < 25; ++i) {
      int h = wave * 25 + i;
      const float4* r = (const float4*)(hb + (size_t)h * DD);
      float p = dot4(r[lane], v0) + dot4(r[lane + 64], v1) + dot4(r[lane + 128], v2);
      for (int off = 32; off; off >>= 1) p += __shfl_down(p, off, 64);
      if (lane == 0) sal[h] = p;
    }
  }
  __syncthreads();
  // softmax over 100 (wave 0; lanes hold h=lane and h=lane+64)
  if (wave == 0) {
    float x0 = (lane < HH) ? sal[lane] : -1e30f;
    float x1 = (lane + 64 < HH) ? sal[lane + 64] : -1e30f;
    float m = fmaxf(x0, x1);
    for (int off = 32; off; off >>= 1) m = fmaxf(m, __shfl_xor(m, off, 64));
    float e0 = (lane < HH) ? __expf(x0 - m) : 0.f;
    float e1 = (lane + 64 < HH) ? __expf(x1 - m) : 0.f;
    float s = e0 + e1;
    for (int off = 32; off; off >>= 1) s += __shfl_xor(s, off, 64);
    float inv = 1.f / s;
    if (lane < HH) sal[lane] = e0 * inv;
    if (lane + 64 < HH) sal[lane + 64] = e1 * inv;
  }
  __syncthreads();
  // wsum for this block's 256-col slice
  {
    int e = es * 256 + tid;
    const float* hb = hist + (size_t)b * HH * DD + e;
    float acc = 0.f;
    for (int h = 0; h < HH; h += 4) {  // 100 % 4 == 0
      float v0 = hb[(size_t)(h + 0) * DD];
      float v1 = hb[(size_t)(h + 1) * DD];
      float v2 = hb[(size_t)(h + 2) * DD];
      float v3 = hb[(size_t)(h + 3) * DD];
      acc += sal[h + 0] * v0 + sal[h + 1] * v1 + sal[h + 2] * v2 + sal[h + 3] * v3;
    }
    wsum[(size_t)b * DD + e] = acc;
  }
}

// ---------------------------------------------------------------------------
// D5 k_out: out[b,*,d] = bl[d] + Wl[d,:]·neighf[b] + Wr[d,:]·wsum[b]
// dual-stream dot + LDS stage + 128-way broadcast write. grid (24, 32).
// ---------------------------------------------------------------------------
__global__ void k_out(const float* __restrict__ neighf, const float* __restrict__ wsum,
                      const float* __restrict__ Wl, const float* __restrict__ Wr,
                      const float* __restrict__ bl, float* __restrict__ out) {
  int d0 = blockIdx.x * 32;
  int b0 = blockIdx.y * 3;
  int lane = threadIdx.x & 63, wave = threadIdx.x >> 6;
  __shared__ __align__(16) float s_o[3][32];
  float4 xn[3][3], xw[3][3];
#pragma unroll
  for (int bi = 0; bi < 3; ++bi)
#pragma unroll
    for (int jj = 0; jj < 3; ++jj) {
      int idx = lane + 64 * jj;
      xn[bi][jj] = ((const float4*)(neighf + (size_t)(b0 + bi) * DD))[idx];
      xw[bi][jj] = ((const float4*)(wsum + (size_t)(b0 + bi) * DD))[idx];
    }
  for (int i = 0; i < 8; ++i) {
    int d = d0 + wave * 8 + i;
    const float4* wl4 = (const float4*)(Wl + (size_t)d * DD);
    const float4* wr4 = (const float4*)(Wr + (size_t)d * DD);
    float p[3] = {0.f, 0.f, 0.f};
#pragma unroll
    for (int jj = 0; jj < 3; ++jj) {
      float4 wl = wl4[lane + 64 * jj];
      float4 wr = wr4[lane + 64 * jj];
#pragma unroll
      for (int bi = 0; bi < 3; ++bi)
        p[bi] += dot4(wl, xn[bi][jj]) + dot4(wr, xw[bi][jj]);
    }
#pragma unroll
    for (int bi = 0; bi < 3; ++bi) {
      float pp = p[bi];
      for (int off = 32; off; off >>= 1) pp += __shfl_down(pp, off, 64);
      if (lane == 0) s_o[bi][wave * 8 + i] = pp + bl[d];
    }
  }
  __syncthreads();
  // Broadcast: 3 b x 128 n x 8 float4 = 3072 float4 writes, 12 per thread.
  float4* out4 = (float4*)out;
  int d4 = d0 >> 2;
#pragma unroll
  for (int k = 0; k < 12; ++k) {
    int g = threadIdx.x + (k << 8);
    int seg = g >> 3, off = g & 7;
    int bi = seg >> 7, n = seg & 127;
    float4 val = *(const float4*)&s_o[bi][off * 4];
    out4[((size_t)(b0 + bi) * NN + n) * (DD / 4) + d4 + off] = val;
  }
}

// ---------------------------------------------------------------------------
extern "C" void kernel_launch(void* const* d_in, const int* in_sizes, int n_in,
                              void* d_out, int out_size, void* d_ws, size_t ws_size,
                              hipStream_t stream) {
  const float *hist = nullptr, *Wl = nullptr, *Wr = nullptr, *WK = nullptr,
              *WQ = nullptr, *bl = nullptr, *bQ = nullptr;
  int seenDxD = 0, seenAxD = 0;
  for (int i = 0; i < n_in; ++i) {
    int s = in_sizes[i];
    const float* p = (const float*)d_in[i];
    if (s == BB * HH * DD) hist = p;
    else if (s == BB * NN * DD) { /* candidate — unused */ }
    else if (s == DD * DD) { if (seenDxD++ == 0) Wl = p; else Wr = p; }
    else if (s == AA * DD) { if (seenAxD++ == 0) WK = p; else WQ = p; }
    else if (s == DD) bl = p;
    else if (s == AA) bQ = p;
  }

  float* ws = (float*)d_ws;
  float* Nm     = ws + 0;         // 256*768 = 196608
  float* WA     = ws + 196608;    // 196608
  float* WB     = ws + 393216;    // 196608
  float* c2     = ws + 589824;    // 256
  float* neighp = ws + 590080;    // 8*96*768 = 589824
  float* neighf = ws + 1179904;   // 73728
  float* VA     = ws + 1253632;   // 589824
  float* VB     = ws + 1843456;   // 589824
  float* cv     = ws + 2433280;   // 768
  float* vv     = ws + 2434048;   // 73728
  float* wsum   = ws + 2507776;   // 73728  -> total ~10.3 MB
  float* out = (float*)d_out;

  k_p1  <<<dim3(1352),   dim3(256), 0, stream>>>(Wr, Wl, WK, WQ, bl, bQ, hist,
                                                 Nm, WA, WB, c2, neighp);
  k_p2  <<<dim3(1272),   dim3(256), 0, stream>>>(Nm, WA, WB, c2, neighp,
                                                 VA, VB, cv, neighf);
  k_v   <<<dim3(24, 32), dim3(256), 0, stream>>>(hist, neighf, VA, VB, cv, vv);
  k_attn<<<dim3(96, 3),  dim3(256), 0, stream>>>(hist, vv, wsum);
  k_out <<<dim3(24, 32), dim3(256), 0, stream>>>(neighf, wsum, Wl, Wr, bl, out);
}

// Round 12
// 126.858 us; speedup vs baseline: 1.1169x; 1.1169x over previous
//
#include <hip/hip_runtime.h>
#include <hip/hip_bf16.h>

// Problem constants
#define BB 96    // batch
#define HH 100   // history length
#define NN 128   // candidates (broadcast only)
#define DD 768   // embed dim
#define AA 256   // attention dim

#define WSLAB 196608  // 256*768, one partial GEMM slab

static __device__ __forceinline__ float dot4(float4 a, float4 b) {
  return a.x * b.x + a.y * b.y + a.z * b.z + a.w * b.w;
}

// ---------------------------------------------------------------------------
// D1 k_p1 (3080 blocks): gen-1 weight GEMMs (split-K-4) + neigh partials + c2
//   [0,2304)    : Pp[which][s][a,d] = sum_{e in slab s} L[a,e]*R[e,d]
//                 which=0: N=WK@Wr; 1: WA=WQ@Wr; 2: WB=WQ@Wl
//                 192 tiles (32x32) x 4 K-slabs each -> 6 K-tiles per block
//   [2304,3072) : neigh partials, 8 h-groups x 96 b (12 h each)
//   [3072,3080) : c2[a] = WQ[a,:]·bl + bQ[a]
// ---------------------------------------------------------------------------
__global__ void __launch_bounds__(256)
k_p1(const float* __restrict__ Wr, const float* __restrict__ Wl,
     const float* __restrict__ WK, const float* __restrict__ WQ,
     const float* __restrict__ bl, const float* __restrict__ bQ,
     const float* __restrict__ hist,
     float* __restrict__ Pp, float* __restrict__ c2, float* __restrict__ neighp) {
  int bid = blockIdx.x, tid = threadIdx.x;
  if (bid < 2304) {
    __shared__ float sL[32][33];  // [a][e] tile
    __shared__ float sR[32][33];  // [e][d] tile
    int which = bid / 768;
    int rem = bid % 768;
    int s = rem / 192;            // K-slab (e in [s*192, s*192+192))
    int t = rem % 192;
    const float* L = (which == 0) ? WK : WQ;
    const float* R = (which == 2) ? Wl : Wr;
    float* O = Pp + ((size_t)which * 4 + s) * WSLAB;
    int d0 = (t % 24) * 32, a0 = (t / 24) * 32;
    int tx = tid & 31, ty = tid >> 5;  // 32 x 8
    float acc[4] = {0.f, 0.f, 0.f, 0.f};
    int ebase = s * 192;
    for (int e0 = ebase; e0 < ebase + 192; e0 += 32) {  // 6 K-tiles
#pragma unroll
      for (int k = 0; k < 4; ++k) {
        sL[ty + 8 * k][tx] = L[(size_t)(a0 + ty + 8 * k) * DD + e0 + tx];
        sR[ty + 8 * k][tx] = R[(size_t)(e0 + ty + 8 * k) * DD + d0 + tx];
      }
      __syncthreads();
#pragma unroll 8
      for (int e = 0; e < 32; ++e) {
        float w = sR[e][tx];
#pragma unroll
        for (int k = 0; k < 4; ++k) acc[k] += sL[ty + 8 * k][e] * w;
      }
      __syncthreads();
    }
#pragma unroll
    for (int k = 0; k < 4; ++k)   // O[a,d], coalesced over tx
      O[(size_t)(a0 + ty + 8 * k) * DD + d0 + tx] = acc[k];
  } else if (bid < 3072) {
    int id = bid - 2304;
    int b = id % BB, hg = id / BB;  // 8 h-groups of 12
    if (tid < 192) {
      const float* hb = hist + (size_t)b * HH * DD + (size_t)hg * 12 * DD + tid * 4;
      float4 acc = make_float4(0.f, 0.f, 0.f, 0.f);
#pragma unroll
      for (int i = 0; i < 12; ++i) {
        float4 x = *(const float4*)(hb + (size_t)i * DD);
        acc.x += x.x; acc.y += x.y; acc.z += x.z; acc.w += x.w;
      }
      *(float4*)(neighp + ((size_t)hg * BB + b) * DD + tid * 4) = acc;
    }
  } else {
    int a0 = (bid - 3072) * 32;
    int lane = tid & 63, wave = tid >> 6;
    float4 x0 = ((const float4*)bl)[lane];
    float4 x1 = ((const float4*)bl)[lane + 64];
    float4 x2 = ((const float4*)bl)[lane + 128];
    for (int i = 0; i < 8; ++i) {
      int a = a0 + wave * 8 + i;
      const float4* w4 = (const float4*)(WQ + (size_t)a * DD);
      float p = dot4(w4[lane], x0) + dot4(w4[lane + 64], x1) + dot4(w4[lane + 128], x2);
      for (int off = 32; off; off >>= 1) p += __shfl_down(p, off, 64);
      if (lane == 0) c2[a] = p + bQ[a];
    }
  }
}

// ---------------------------------------------------------------------------
// D2 k_p2 (1272 blocks): gen-2 (4-slab sums folded into tile loads)
//   [0,1152)    : VA[d,e] = sum_a N[a,d]*WA[a,e] (which=0) / VB with WB (=1)
//                 K = 256 -> 8 K-tiles; N/WA/WB read as sum of 4 slabs (L2)
//   [1152,1176) : cv[d] = sum_a N[a,d]*c2[a]
//   [1176,1272) : neighf[b,:] = (1/96) * sum_g neighp[g][b,:]
// ---------------------------------------------------------------------------
__global__ void __launch_bounds__(256)
k_p2(const float* __restrict__ Pp, const float* __restrict__ c2,
     const float* __restrict__ neighp,
     float* __restrict__ VA, float* __restrict__ VB, float* __restrict__ cv,
     float* __restrict__ neighf) {
  int bid = blockIdx.x, tid = threadIdx.x;
  const float* Np0 = Pp;                     // N slabs 0..3
  if (bid < 1152) {
    __shared__ float sN[32][33];  // [a][d] tile
    __shared__ float sA[32][33];  // [a][e] tile
    int which = bid / 576, t = bid % 576;
    const float* Rp0 = Pp + (size_t)(which + 1) * 4 * WSLAB;  // WA or WB slabs
    float* O = (which == 0) ? VA : VB;
    int e0 = (t % 24) * 32, d0 = (t / 24) * 32;
    int tx = tid & 31, ty = tid >> 5;
    float acc[4] = {0.f, 0.f, 0.f, 0.f};
    for (int a0 = 0; a0 < AA; a0 += 32) {  // 8 K-tiles
#pragma unroll
      for (int k = 0; k < 4; ++k) {
        size_t rowN = (size_t)(a0 + ty + 8 * k) * DD + d0 + tx;
        size_t rowA = (size_t)(a0 + ty + 8 * k) * DD + e0 + tx;
        sN[ty + 8 * k][tx] = Np0[rowN] + Np0[WSLAB + rowN] +
                             Np0[2 * WSLAB + rowN] + Np0[3 * WSLAB + rowN];
        sA[ty + 8 * k][tx] = Rp0[rowA] + Rp0[WSLAB + rowA] +
                             Rp0[2 * WSLAB + rowA] + Rp0[3 * WSLAB + rowA];
      }
      __syncthreads();
#pragma unroll 8
      for (int a = 0; a < 32; ++a) {
        float w = sA[a][tx];
#pragma unroll
        for (int k = 0; k < 4; ++k) acc[k] += sN[a][ty + 8 * k] * w;
      }
      __syncthreads();
    }
#pragma unroll
    for (int k = 0; k < 4; ++k)   // O[d,e], coalesced over tx
      O[(size_t)(d0 + ty + 8 * k) * DD + e0 + tx] = acc[k];
  } else if (bid < 1176) {
    __shared__ float sc2[AA];
    __shared__ float sred[8][32];
    int d0 = (bid - 1152) * 32;
    if (tid < AA) sc2[tid] = c2[tid];
    __syncthreads();
    int dl = tid & 31, g = tid >> 5;  // 8 groups x 32 a each
    float acc = 0.f;
#pragma unroll 8
    for (int i = 0; i < 32; ++i) {
      int a = g * 32 + i;
      size_t row = (size_t)a * DD + d0 + dl;
      float nv = Np0[row] + Np0[WSLAB + row] + Np0[2 * WSLAB + row] + Np0[3 * WSLAB + row];
      acc += nv * sc2[a];
    }
    sred[g][dl] = acc;
    __syncthreads();
    if (tid < 32) {
      float s = 0.f;
#pragma unroll
      for (int gg = 0; gg < 8; ++gg) s += sred[gg][tid];
      cv[d0 + tid] = s;
    }
  } else {
    int b = bid - 1176;
    if (tid < 192) {
      float4 s = make_float4(0.f, 0.f, 0.f, 0.f);
#pragma unroll
      for (int g = 0; g < 8; ++g) {
        float4 x = ((const float4*)(neighp + ((size_t)g * BB + b) * DD))[tid];
        s.x += x.x; s.y += x.y; s.z += x.z; s.w += x.w;
      }
      float4 m = make_float4(s.x * (1.f / 96.f), s.y * (1.f / 96.f),
                             s.z * (1.f / 96.f), s.w * (1.f / 96.f));
      ((float4*)(neighf + (size_t)b * DD))[tid] = m;
    }
  }
}

// ---------------------------------------------------------------------------
// D3 k_v: v[b,d] = (VA[d,:]·hist0[b] + VB[d,:]·neighf[b] + cv[d]) / 16
// dual-stream wave-split-K, 3 b/thread, 32 d/block, grid (24, 32)
// ---------------------------------------------------------------------------
__global__ void k_v(const float* __restrict__ hist, const float* __restrict__ neighf,
                    const float* __restrict__ VA, const float* __restrict__ VB,
                    const float* __restrict__ cv, float* __restrict__ vv) {
  int d0 = blockIdx.x * 32;
  int b0 = blockIdx.y * 3;
  int lane = threadIdx.x & 63, wave = threadIdx.x >> 6;
  float4 xh[3][3], xn[3][3];
#pragma unroll
  for (int bi = 0; bi < 3; ++bi) {
    int b = b0 + bi;
#pragma unroll
    for (int jj = 0; jj < 3; ++jj) {
      int idx = lane + 64 * jj;
      xh[bi][jj] = ((const float4*)(hist + (size_t)b * HH * DD))[idx];  // h=0 row
      xn[bi][jj] = ((const float4*)(neighf + (size_t)b * DD))[idx];
    }
  }
  for (int i = 0; i < 8; ++i) {
    int d = d0 + wave * 8 + i;
    const float4* va4 = (const float4*)(VA + (size_t)d * DD);
    const float4* vb4 = (const float4*)(VB + (size_t)d * DD);
    float pa[3] = {0.f, 0.f, 0.f}, pb[3] = {0.f, 0.f, 0.f};
#pragma unroll
    for (int jj = 0; jj < 3; ++jj) {
      float4 wa = va4[lane + 64 * jj];
      float4 wb = vb4[lane + 64 * jj];
#pragma unroll
      for (int bi = 0; bi < 3; ++bi) {
        pa[bi] += dot4(wa, xh[bi][jj]);
        pb[bi] += dot4(wb, xn[bi][jj]);
      }
    }
#pragma unroll
    for (int bi = 0; bi < 3; ++bi) {
      float pp = pa[bi] + pb[bi];
      for (int off = 32; off; off >>= 1) pp += __shfl_down(pp, off, 64);
      if (lane == 0)
        vv[(size_t)(b0 + bi) * DD + d] = (pp + cv[d]) * (1.f / 16.f);
    }
  }
}

// ---------------------------------------------------------------------------
// D4 k_attn: fused scores -> softmax -> wsum.  grid (96, 3), 256 threads.
// ---------------------------------------------------------------------------
__global__ void __launch_bounds__(256)
k_attn(const float* __restrict__ hist, const float* __restrict__ vv,
       float* __restrict__ wsum) {
  int b = blockIdx.x;
  int es = blockIdx.y;
  int tid = threadIdx.x, lane = tid & 63, wave = tid >> 6;
  __shared__ __align__(16) float sv[DD];
  __shared__ float sal[HH];
  if (tid < 192)
    ((float4*)sv)[tid] = ((const float4*)(vv + (size_t)b * DD))[tid];
  __syncthreads();
  // scores: 4 waves x 25 h
  {
    float4 v0 = ((const float4*)sv)[lane];
    float4 v1 = ((const float4*)sv)[lane + 64];
    float4 v2 = ((const float4*)sv)[lane + 128];
    const float* hb = hist + (size_t)b * HH * DD;
    for (int i = 0; i < 25; ++i) {
      int h = wave * 25 + i;
      const float4* r = (const float4*)(hb + (size_t)h * DD);
      float p = dot4(r[lane], v0) + dot4(r[lane + 64], v1) + dot4(r[lane + 128], v2);
      for (int off = 32; off; off >>= 1) p += __shfl_down(p, off, 64);
      if (lane == 0) sal[h] = p;
    }
  }
  __syncthreads();
  // softmax over 100 (wave 0; lanes hold h=lane and h=lane+64)
  if (wave == 0) {
    float x0 = (lane < HH) ? sal[lane] : -1e30f;
    float x1 = (lane + 64 < HH) ? sal[lane + 64] : -1e30f;
    float m = fmaxf(x0, x1);
    for (int off = 32; off; off >>= 1) m = fmaxf(m, __shfl_xor(m, off, 64));
    float e0 = (lane < HH) ? __expf(x0 - m) : 0.f;
    float e1 = (lane + 64 < HH) ? __expf(x1 - m) : 0.f;
    float s = e0 + e1;
    for (int off = 32; off; off >>= 1) s += __shfl_xor(s, off, 64);
    float inv = 1.f / s;
    if (lane < HH) sal[lane] = e0 * inv;
    if (lane + 64 < HH) sal[lane + 64] = e1 * inv;
  }
  __syncthreads();
  // wsum for this block's 256-col slice
  {
    int e = es * 256 + tid;
    const float* hb = hist + (size_t)b * HH * DD + e;
    float acc = 0.f;
    for (int h = 0; h < HH; h += 4) {  // 100 % 4 == 0
      float v0 = hb[(size_t)(h + 0) * DD];
      float v1 = hb[(size_t)(h + 1) * DD];
      float v2 = hb[(size_t)(h + 2) * DD];
      float v3 = hb[(size_t)(h + 3) * DD];
      acc += sal[h + 0] * v0 + sal[h + 1] * v1 + sal[h + 2] * v2 + sal[h + 3] * v3;
    }
    wsum[(size_t)b * DD + e] = acc;
  }
}

// ---------------------------------------------------------------------------
// D5 k_out: out[b,*,d] = bl[d] + Wl[d,:]·neighf[b] + Wr[d,:]·wsum[b]
// dual-stream dot + LDS stage + 128-way broadcast write. grid (24, 32).
// ---------------------------------------------------------------------------
__global__ void k_out(const float* __restrict__ neighf, const float* __restrict__ wsum,
                      const float* __restrict__ Wl, const float* __restrict__ Wr,
                      const float* __restrict__ bl, float* __restrict__ out) {
  int d0 = blockIdx.x * 32;
  int b0 = blockIdx.y * 3;
  int lane = threadIdx.x & 63, wave = threadIdx.x >> 6;
  __shared__ __align__(16) float s_o[3][32];
  float4 xn[3][3], xw[3][3];
#pragma unroll
  for (int bi = 0; bi < 3; ++bi)
#pragma unroll
    for (int jj = 0; jj < 3; ++jj) {
      int idx = lane + 64 * jj;
      xn[bi][jj] = ((const float4*)(neighf + (size_t)(b0 + bi) * DD))[idx];
      xw[bi][jj] = ((const float4*)(wsum + (size_t)(b0 + bi) * DD))[idx];
    }
  for (int i = 0; i < 8; ++i) {
    int d = d0 + wave * 8 + i;
    const float4* wl4 = (const float4*)(Wl + (size_t)d * DD);
    const float4* wr4 = (const float4*)(Wr + (size_t)d * DD);
    float p[3] = {0.f, 0.f, 0.f};
#pragma unroll
    for (int jj = 0; jj < 3; ++jj) {
      float4 wl = wl4[lane + 64 * jj];
      float4 wr = wr4[lane + 64 * jj];
#pragma unroll
      for (int bi = 0; bi < 3; ++bi)
        p[bi] += dot4(wl, xn[bi][jj]) + dot4(wr, xw[bi][jj]);
    }
#pragma unroll
    for (int bi = 0; bi < 3; ++bi) {
      float pp = p[bi];
      for (int off = 32; off; off >>= 1) pp += __shfl_down(pp, off, 64);
      if (lane == 0) s_o[bi][wave * 8 + i] = pp + bl[d];
    }
  }
  __syncthreads();
  // Broadcast: 3 b x 128 n x 8 float4 = 3072 float4 writes, 12 per thread.
  float4* out4 = (float4*)out;
  int d4 = d0 >> 2;
#pragma unroll
  for (int k = 0; k < 12; ++k) {
    int g = threadIdx.x + (k << 8);
    int seg = g >> 3, off = g & 7;
    int bi = seg >> 7, n = seg & 127;
    float4 val = *(const float4*)&s_o[bi][off * 4];
    out4[((size_t)(b0 + bi) * NN + n) * (DD / 4) + d4 + off] = val;
  }
}

// ---------------------------------------------------------------------------
extern "C" void kernel_launch(void* const* d_in, const int* in_sizes, int n_in,
                              void* d_out, int out_size, void* d_ws, size_t ws_size,
                              hipStream_t stream) {
  const float *hist = nullptr, *Wl = nullptr, *Wr = nullptr, *WK = nullptr,
              *WQ = nullptr, *bl = nullptr, *bQ = nullptr;
  int seenDxD = 0, seenAxD = 0;
  for (int i = 0; i < n_in; ++i) {
    int s = in_sizes[i];
    const float* p = (const float*)d_in[i];
    if (s == BB * HH * DD) hist = p;
    else if (s == BB * NN * DD) { /* candidate — unused */ }
    else if (s == DD * DD) { if (seenDxD++ == 0) Wl = p; else Wr = p; }
    else if (s == AA * DD) { if (seenAxD++ == 0) WK = p; else WQ = p; }
    else if (s == DD) bl = p;
    else if (s == AA) bQ = p;
  }

  float* ws = (float*)d_ws;
  float* Pp     = ws + 0;         // 3 which * 4 slabs * 196608 = 2359296
  float* c2     = ws + 2359296;   // 256
  float* neighp = ws + 2359552;   // 8*96*768 = 589824
  float* neighf = ws + 2949376;   // 73728
  float* VA     = ws + 3023104;   // 589824
  float* VB     = ws + 3612928;   // 589824
  float* cv     = ws + 4202752;   // 768
  float* vv     = ws + 4203520;   // 73728
  float* wsum   = ws + 4277248;   // 73728  -> total ~17.4 MB
  float* out = (float*)d_out;

  k_p1  <<<dim3(3080),   dim3(256), 0, stream>>>(Wr, Wl, WK, WQ, bl, bQ, hist,
                                                 Pp, c2, neighp);
  k_p2  <<<dim3(1272),   dim3(256), 0, stream>>>(Pp, c2, neighp, VA, VB, cv, neighf);
  k_v   <<<dim3(24, 32), dim3(256), 0, stream>>>(hist, neighf, VA, VB, cv, vv);
  k_attn<<<dim3(96, 3),  dim3(256), 0, stream>>>(hist, vv, wsum);
  k_out <<<dim3(24, 32), dim3(256), 0, stream>>>(neighf, wsum, Wl, Wr, bl, out);
}

// Round 13
// 99.218 us; speedup vs baseline: 1.4281x; 1.2786x over previous
//
#include <hip/hip_runtime.h>
#include <hip/hip_bf16.h>

// Problem constants
#define BB 96    // batch
#define HH 100   // history length
#define NN 128   // candidates (broadcast only)
#define DD 768   // embed dim
#define AA 256   // attention dim

#define WSLAB 196608   // 768*256, one MT partial slab (floats)
#define WSLAB4 49152   // in float4

static __device__ __forceinline__ float dot4(float4 a, float4 b) {
  return a.x * b.x + a.y * b.y + a.z * b.z + a.w * b.w;
}

// ---------------------------------------------------------------------------
// D1 k_prep (1536 blocks):
//   [0,768)    : MTp[s][d,a] = sum_{e in slab s} WK[a,e]*Wr[e,d]
//                split-K-4: 192 tiles (32x32) x 4 slabs -> 6 K-tiles/block.
//                Output transposed through LDS -> coalesced d-major writes.
//   [768,1536) : neigh partials, 8 h-groups x 96 b (12 h each)
// ---------------------------------------------------------------------------
__global__ void __launch_bounds__(256)
k_prep(const float* __restrict__ Wr, const float* __restrict__ WK,
       const float* __restrict__ hist,
       float* __restrict__ MTp, float* __restrict__ neighp) {
  int bid = blockIdx.x, tid = threadIdx.x;
  if (bid < 768) {
    __shared__ float sL[32][33];  // [a][e] tile (reused as transpose stage)
    __shared__ float sR[32][33];  // [e][d] tile
    int s = bid / 192;            // K-slab (e in [s*192, s*192+192))
    int t = bid % 192;
    int d0 = (t % 24) * 32, a0 = (t / 24) * 32;
    int tx = tid & 31, ty = tid >> 5;  // 32 x 8
    float acc[4] = {0.f, 0.f, 0.f, 0.f};
    int ebase = s * 192;
    for (int e0 = ebase; e0 < ebase + 192; e0 += 32) {  // 6 K-tiles
#pragma unroll
      for (int k = 0; k < 4; ++k) {
        sL[ty + 8 * k][tx] = WK[(size_t)(a0 + ty + 8 * k) * DD + e0 + tx];
        sR[ty + 8 * k][tx] = Wr[(size_t)(e0 + ty + 8 * k) * DD + d0 + tx];
      }
      __syncthreads();
#pragma unroll 8
      for (int e = 0; e < 32; ++e) {
        float w = sR[e][tx];
#pragma unroll
        for (int k = 0; k < 4; ++k) acc[k] += sL[ty + 8 * k][e] * w;
      }
      __syncthreads();
    }
    // transpose stage: sL[a_local][d_local] = acc, then d-major coalesced write
#pragma unroll
    for (int k = 0; k < 4; ++k) sL[ty + 8 * k][tx] = acc[k];
    __syncthreads();
    float* MTs = MTp + (size_t)s * WSLAB;
#pragma unroll
    for (int k = 0; k < 4; ++k)   // row d = d0+ty+8k, cols a0+tx (coalesced)
      MTs[(size_t)(d0 + ty + 8 * k) * AA + a0 + tx] = sL[tx][ty + 8 * k];
  } else {
    int id = bid - 768;
    int b = id % BB, hg = id / BB;  // 8 h-groups of 12
    if (tid < 192) {
      const float* hb = hist + (size_t)b * HH * DD + (size_t)hg * 12 * DD + tid * 4;
      float4 acc = make_float4(0.f, 0.f, 0.f, 0.f);
#pragma unroll
      for (int i = 0; i < 12; ++i) {
        float4 x = *(const float4*)(hb + (size_t)i * DD);
        acc.x += x.x; acc.y += x.y; acc.z += x.z; acc.w += x.w;
      }
      *(float4*)(neighp + ((size_t)hg * BB + b) * DD + tid * 4) = acc;
    }
  }
}

// ---------------------------------------------------------------------------
// D2 k_nl_u0: nl[b,e] = neigh[b,:]·W_l[e,:] + b_l[e];
//             u0[b,e] = hist[b,0,:]·W_r[e,:] + nl[b,e]
// neigh = (1/96) * sum of 8 neighp slabs (summed inline, r5-proven).
// wave-split-K, 3 b/thread, 32 e/block, grid (24, 32)
// ---------------------------------------------------------------------------
__global__ void k_nl_u0(const float* __restrict__ neighp, const float* __restrict__ hist,
                        const float* __restrict__ Wl, const float* __restrict__ bl,
                        const float* __restrict__ Wr,
                        float* __restrict__ nl, float* __restrict__ u0) {
  int e0 = blockIdx.x * 32;
  int b0 = blockIdx.y * 3;
  int lane = threadIdx.x & 63, wave = threadIdx.x >> 6;
  float4 xn[3][3], xh[3][3];
#pragma unroll
  for (int bi = 0; bi < 3; ++bi) {
    int b = b0 + bi;
#pragma unroll
    for (int jj = 0; jj < 3; ++jj) {
      int idx = lane + 64 * jj;
      float4 s = make_float4(0.f, 0.f, 0.f, 0.f);
#pragma unroll
      for (int g = 0; g < 8; ++g) {
        float4 x = ((const float4*)(neighp + ((size_t)g * BB + b) * DD))[idx];
        s.x += x.x; s.y += x.y; s.z += x.z; s.w += x.w;
      }
      xn[bi][jj] = make_float4(s.x * (1.f / 96.f), s.y * (1.f / 96.f),
                               s.z * (1.f / 96.f), s.w * (1.f / 96.f));
      xh[bi][jj] = ((const float4*)(hist + (size_t)b * HH * DD))[idx];  // h=0 row
    }
  }
  for (int i = 0; i < 8; ++i) {
    int e = e0 + wave * 8 + i;
    const float4* wl4 = (const float4*)(Wl + (size_t)e * DD);
    const float4* wr4 = (const float4*)(Wr + (size_t)e * DD);
    float pl[3] = {0.f, 0.f, 0.f}, pr[3] = {0.f, 0.f, 0.f};
#pragma unroll
    for (int jj = 0; jj < 3; ++jj) {
      float4 wl = wl4[lane + 64 * jj];
      float4 wr = wr4[lane + 64 * jj];
#pragma unroll
      for (int bi = 0; bi < 3; ++bi) {
        pl[bi] += dot4(wl, xn[bi][jj]);
        pr[bi] += dot4(wr, xh[bi][jj]);
      }
    }
#pragma unroll
    for (int bi = 0; bi < 3; ++bi) {
      float pp = pl[bi], qq = pr[bi];
      for (int off = 32; off; off >>= 1) {
        pp += __shfl_down(pp, off, 64);
        qq += __shfl_down(qq, off, 64);
      }
      if (lane == 0) {
        float nle = pp + bl[e];
        nl[(size_t)(b0 + bi) * DD + e] = nle;
        u0[(size_t)(b0 + bi) * DD + e] = qq + nle;
      }
    }
  }
}

// ---------------------------------------------------------------------------
// D3 k_q (448 blocks flat):
//   [0,256)   : Q[b,a] = u0[b,:]·W_Q[a,:] + b_Q[a]  (a0=(bid&7)*32, b0=(bid>>3)*3)
//   [256,448) : MT = MTp[0]+MTp[1]+MTp[2]+MTp[3]  (float4 elementwise)
// ---------------------------------------------------------------------------
__global__ void __launch_bounds__(256)
k_q(const float* __restrict__ u0, const float* __restrict__ WQ,
    const float* __restrict__ bQ, const float* __restrict__ MTp,
    float* __restrict__ Qm, float* __restrict__ MT) {
  int bid = blockIdx.x, tid = threadIdx.x;
  if (bid < 256) {
    int a0 = (bid & 7) * 32;
    int b0 = (bid >> 3) * 3;
    int lane = tid & 63, wave = tid >> 6;
    float4 x[3][3];
#pragma unroll
    for (int bi = 0; bi < 3; ++bi)
#pragma unroll
      for (int jj = 0; jj < 3; ++jj)
        x[bi][jj] = ((const float4*)(u0 + (size_t)(b0 + bi) * DD))[lane + 64 * jj];
    for (int i = 0; i < 8; ++i) {
      int a = a0 + wave * 8 + i;
      const float4* w4 = (const float4*)(WQ + (size_t)a * DD);
      float p[3] = {0.f, 0.f, 0.f};
#pragma unroll
      for (int jj = 0; jj < 3; ++jj) {
        float4 w = w4[lane + 64 * jj];
#pragma unroll
        for (int bi = 0; bi < 3; ++bi) p[bi] += dot4(w, x[bi][jj]);
      }
#pragma unroll
      for (int bi = 0; bi < 3; ++bi) {
        float pp = p[bi];
        for (int off = 32; off; off >>= 1) pp += __shfl_down(pp, off, 64);
        if (lane == 0) Qm[(size_t)(b0 + bi) * AA + a] = pp + bQ[a];
      }
    }
  } else {
    int i4 = (bid - 256) * 256 + tid;  // float4 index, 192*256 = 49152 total
    const float4* p = (const float4*)MTp;
    float4 a = p[i4], b = p[WSLAB4 + i4], c = p[2 * WSLAB4 + i4], d = p[3 * WSLAB4 + i4];
    ((float4*)MT)[i4] = make_float4(a.x + b.x + c.x + d.x, a.y + b.y + c.y + d.y,
                                    a.z + b.z + c.z + d.z, a.w + b.w + c.w + d.w);
  }
}

// ---------------------------------------------------------------------------
// D4 k_v: v[b,d] = (1/16) * Q[b,:]·MT[d,:]   grid (24, 32)   (K = 256)
// ---------------------------------------------------------------------------
__global__ void k_v(const float* __restrict__ Qm, const float* __restrict__ MT,
                    float* __restrict__ vv) {
  int d0 = blockIdx.x * 32;
  int b0 = blockIdx.y * 3;
  int lane = threadIdx.x & 63, wave = threadIdx.x >> 6;
  float4 x[3];
#pragma unroll
  for (int bi = 0; bi < 3; ++bi)
    x[bi] = ((const float4*)(Qm + (size_t)(b0 + bi) * AA))[lane];
  for (int i = 0; i < 8; ++i) {
    int d = d0 + wave * 8 + i;
    float4 w = ((const float4*)(MT + (size_t)d * AA))[lane];
    float p[3];
#pragma unroll
    for (int bi = 0; bi < 3; ++bi) p[bi] = dot4(w, x[bi]);
#pragma unroll
    for (int bi = 0; bi < 3; ++bi) {
      float pp = p[bi];
      for (int off = 32; off; off >>= 1) pp += __shfl_down(pp, off, 64);
      if (lane == 0) vv[(size_t)(b0 + bi) * DD + d] = pp * (1.f / 16.f);
    }
  }
}

// ---------------------------------------------------------------------------
// D5 k_attn: fused scores -> softmax -> wsum.  grid (96, 3), 256 threads.
// ---------------------------------------------------------------------------
__global__ void __launch_bounds__(256)
k_attn(const float* __restrict__ hist, const float* __restrict__ vv,
       float* __restrict__ wsum) {
  int b = blockIdx.x;
  int es = blockIdx.y;
  int tid = threadIdx.x, lane = tid & 63, wave = tid >> 6;
  __shared__ __align__(16) float sv[DD];
  __shared__ float sal[HH];
  if (tid < 192)
    ((float4*)sv)[tid] = ((const float4*)(vv + (size_t)b * DD))[tid];
  __syncthreads();
  // scores: 4 waves x 25 h
  {
    float4 v0 = ((const float4*)sv)[lane];
    float4 v1 = ((const float4*)sv)[lane + 64];
    float4 v2 = ((const float4*)sv)[lane + 128];
    const float* hb = hist + (size_t)b * HH * DD;
    for (int i = 0; i < 25; ++i) {
      int h = wave * 25 + i;
      const float4* r = (const float4*)(hb + (size_t)h * DD);
      float p = dot4(r[lane], v0) + dot4(r[lane + 64], v1) + dot4(r[lane + 128], v2);
      for (int off = 32; off; off >>= 1) p += __shfl_down(p, off, 64);
      if (lane == 0) sal[h] = p;
    }
  }
  __syncthreads();
  // softmax over 100 (wave 0; lanes hold h=lane and h=lane+64)
  if (wave == 0) {
    float x0 = (lane < HH) ? sal[lane] : -1e30f;
    float x1 = (lane + 64 < HH) ? sal[lane + 64] : -1e30f;
    float m = fmaxf(x0, x1);
    for (int off = 32; off; off >>= 1) m = fmaxf(m, __shfl_xor(m, off, 64));
    float e0 = (lane < HH) ? __expf(x0 - m) : 0.f;
    float e1 = (lane + 64 < HH) ? __expf(x1 - m) : 0.f;
    float s = e0 + e1;
    for (int off = 32; off; off >>= 1) s += __shfl_xor(s, off, 64);
    float inv = 1.f / s;
    if (lane < HH) sal[lane] = e0 * inv;
    if (lane + 64 < HH) sal[lane + 64] = e1 * inv;
  }
  __syncthreads();
  // wsum for this block's 256-col slice
  {
    int e = es * 256 + tid;
    const float* hb = hist + (size_t)b * HH * DD + e;
    float acc = 0.f;
    for (int h = 0; h < HH; h += 4) {  // 100 % 4 == 0
      float v0 = hb[(size_t)(h + 0) * DD];
      float v1 = hb[(size_t)(h + 1) * DD];
      float v2 = hb[(size_t)(h + 2) * DD];
      float v3 = hb[(size_t)(h + 3) * DD];
      acc += sal[h + 0] * v0 + sal[h + 1] * v1 + sal[h + 2] * v2 + sal[h + 3] * v3;
    }
    wsum[(size_t)b * DD + e] = acc;
  }
}

// ---------------------------------------------------------------------------
// D6 k_orow_write: orow[b,d] = nl[b,d] + wsum[b,:]·W_r[d,:], then broadcast
// directly to out[b, 0..127, d] (via LDS stage). grid (24, 32).
// ---------------------------------------------------------------------------
__global__ void k_orow_write(const float* __restrict__ wsum, const float* __restrict__ Wr,
                             const float* __restrict__ nl, float* __restrict__ out) {
  int d0 = blockIdx.x * 32;
  int b0 = blockIdx.y * 3;
  int lane = threadIdx.x & 63, wave = threadIdx.x >> 6;
  __shared__ __align__(16) float s_o[3][32];
  float4 x[3][3];
#pragma unroll
  for (int bi = 0; bi < 3; ++bi)
#pragma unroll
    for (int jj = 0; jj < 3; ++jj)
      x[bi][jj] = ((const float4*)(wsum + (size_t)(b0 + bi) * DD))[lane + 64 * jj];
  for (int i = 0; i < 8; ++i) {
    int d = d0 + wave * 8 + i;
    const float4* w4 = (const float4*)(Wr + (size_t)d * DD);
    float p[3] = {0.f, 0.f, 0.f};
#pragma unroll
    for (int jj = 0; jj < 3; ++jj) {
      float4 w = w4[lane + 64 * jj];
#pragma unroll
      for (int bi = 0; bi < 3; ++bi) p[bi] += dot4(w, x[bi][jj]);
    }
#pragma unroll
    for (int bi = 0; bi < 3; ++bi) {
      float pp = p[bi];
      for (int off = 32; off; off >>= 1) pp += __shfl_down(pp, off, 64);
      if (lane == 0)
        s_o[bi][wave * 8 + i] = pp + nl[(size_t)(b0 + bi) * DD + d];
    }
  }
  __syncthreads();
  // Broadcast: 3 b x 128 n x 8 float4 = 3072 float4 writes, 12 per thread.
  float4* out4 = (float4*)out;
  int d4 = d0 >> 2;
#pragma unroll
  for (int k = 0; k < 12; ++k) {
    int g = threadIdx.x + (k << 8);
    int seg = g >> 3, off = g & 7;
    int bi = seg >> 7, n = seg & 127;
    float4 val = *(const float4*)&s_o[bi][off * 4];
    out4[((size_t)(b0 + bi) * NN + n) * (DD / 4) + d4 + off] = val;
  }
}

// ---------------------------------------------------------------------------
extern "C" void kernel_launch(void* const* d_in, const int* in_sizes, int n_in,
                              void* d_out, int out_size, void* d_ws, size_t ws_size,
                              hipStream_t stream) {
  const float *hist = nullptr, *Wl = nullptr, *Wr = nullptr, *WK = nullptr,
              *WQ = nullptr, *bl = nullptr, *bQ = nullptr;
  int seenDxD = 0, seenAxD = 0;
  for (int i = 0; i < n_in; ++i) {
    int s = in_sizes[i];
    const float* p = (const float*)d_in[i];
    if (s == BB * HH * DD) hist = p;
    else if (s == BB * NN * DD) { /* candidate — unused */ }
    else if (s == DD * DD) { if (seenDxD++ == 0) Wl = p; else Wr = p; }
    else if (s == AA * DD) { if (seenAxD++ == 0) WK = p; else WQ = p; }
    else if (s == DD) bl = p;
    else if (s == AA) bQ = p;
  }

  float* ws = (float*)d_ws;
  float* MTp    = ws + 0;         // 4 * 196608 = 786432
  float* MT     = ws + 786432;    // 196608
  float* neighp = ws + 983040;    // 8*96*768 = 589824
  float* nl     = ws + 1572864;   // 73728
  float* u0     = ws + 1646592;   // 73728
  float* Qm     = ws + 1720320;   // 24576
  float* vv     = ws + 1744896;   // 73728
  float* wsum   = ws + 1818624;   // 73728  -> total ~7.6 MB
  float* out = (float*)d_out;

  k_prep      <<<dim3(1536),   dim3(256), 0, stream>>>(Wr, WK, hist, MTp, neighp);
  k_nl_u0     <<<dim3(24, 32), dim3(256), 0, stream>>>(neighp, hist, Wl, bl, Wr, nl, u0);
  k_q         <<<dim3(448),    dim3(256), 0, stream>>>(u0, WQ, bQ, MTp, Qm, MT);
  k_v         <<<dim3(24, 32), dim3(256), 0, stream>>>(Qm, MT, vv);
  k_attn      <<<dim3(96, 3),  dim3(256), 0, stream>>>(hist, vv, wsum);
  k_orow_write<<<dim3(24, 32), dim3(256), 0, stream>>>(wsum, Wr, nl, out);
}

// Round 14
// 87.396 us; speedup vs baseline: 1.6213x; 1.1353x over previous
//
#include <hip/hip_runtime.h>
#include <hip/hip_bf16.h>

// Problem constants
#define BB 96    // batch
#define HH 100   // history length
#define NN 128   // candidates (broadcast only)
#define DD 768   // embed dim
#define AA 256   // attention dim

#define WSLAB 196608   // 768*256, one MT partial slab (floats)
#define WSLAB4 49152   // in float4

static __device__ __forceinline__ float dot4(float4 a, float4 b) {
  return a.x * b.x + a.y * b.y + a.z * b.z + a.w * b.w;
}

// ---------------------------------------------------------------------------
// D1 k_prep (1152 blocks):
//   [0,768)     : MTp[s][d,a] = sum_{e in slab s} WK[a,e]*Wr[e,d]
//                 split-K-4: 192 tiles (32x32) x 4 slabs -> 6 K-tiles/block.
//   [768,1152)  : neigh partials, 4 h-groups x 96 b (24 h each)
// ---------------------------------------------------------------------------
__global__ void __launch_bounds__(256)
k_prep(const float* __restrict__ Wr, const float* __restrict__ WK,
       const float* __restrict__ hist,
       float* __restrict__ MTp, float* __restrict__ neighp) {
  int bid = blockIdx.x, tid = threadIdx.x;
  if (bid < 768) {
    __shared__ float sL[32][33];  // [a][e] tile (reused as transpose stage)
    __shared__ float sR[32][33];  // [e][d] tile
    int s = bid / 192;            // K-slab (e in [s*192, s*192+192))
    int t = bid % 192;
    int d0 = (t % 24) * 32, a0 = (t / 24) * 32;
    int tx = tid & 31, ty = tid >> 5;  // 32 x 8
    float acc[4] = {0.f, 0.f, 0.f, 0.f};
    int ebase = s * 192;
    for (int e0 = ebase; e0 < ebase + 192; e0 += 32) {  // 6 K-tiles
#pragma unroll
      for (int k = 0; k < 4; ++k) {
        sL[ty + 8 * k][tx] = WK[(size_t)(a0 + ty + 8 * k) * DD + e0 + tx];
        sR[ty + 8 * k][tx] = Wr[(size_t)(e0 + ty + 8 * k) * DD + d0 + tx];
      }
      __syncthreads();
#pragma unroll 8
      for (int e = 0; e < 32; ++e) {
        float w = sR[e][tx];
#pragma unroll
        for (int k = 0; k < 4; ++k) acc[k] += sL[ty + 8 * k][e] * w;
      }
      __syncthreads();
    }
    // transpose stage -> coalesced d-major writes
#pragma unroll
    for (int k = 0; k < 4; ++k) sL[ty + 8 * k][tx] = acc[k];
    __syncthreads();
    float* MTs = MTp + (size_t)s * WSLAB;
#pragma unroll
    for (int k = 0; k < 4; ++k)
      MTs[(size_t)(d0 + ty + 8 * k) * AA + a0 + tx] = sL[tx][ty + 8 * k];
  } else {
    int id = bid - 768;
    int b = id % BB, hg = id / BB;  // 4 h-groups of 24
    if (tid < 192) {
      const float* hb = hist + (size_t)b * HH * DD + (size_t)hg * 24 * DD + tid * 4;
      float4 a0 = make_float4(0.f, 0.f, 0.f, 0.f);
      float4 a1 = make_float4(0.f, 0.f, 0.f, 0.f);
#pragma unroll
      for (int h = 0; h < 24; h += 2) {
        float4 x = *(const float4*)(hb + (size_t)h * DD);
        float4 y = *(const float4*)(hb + (size_t)(h + 1) * DD);
        a0.x += x.x; a0.y += x.y; a0.z += x.z; a0.w += x.w;
        a1.x += y.x; a1.y += y.y; a1.z += y.z; a1.w += y.w;
      }
      float4 m = make_float4(a0.x + a1.x, a0.y + a1.y, a0.z + a1.z, a0.w + a1.w);
      *(float4*)(neighp + ((size_t)hg * BB + b) * DD + tid * 4) = m;
    }
  }
}

// ---------------------------------------------------------------------------
// D2 k_nl_u0: nl[b,e] = neigh[b,:]·W_l[e,:] + b_l[e];
//             u0[b,e] = hist[b,0,:]·W_r[e,:] + nl[b,e]
// neigh = (1/96) * sum of 4 neighp slabs (inline). grid (24, 32)
// ---------------------------------------------------------------------------
__global__ void k_nl_u0(const float* __restrict__ neighp, const float* __restrict__ hist,
                        const float* __restrict__ Wl, const float* __restrict__ bl,
                        const float* __restrict__ Wr,
                        float* __restrict__ nl, float* __restrict__ u0) {
  int e0 = blockIdx.x * 32;
  int b0 = blockIdx.y * 3;
  int lane = threadIdx.x & 63, wave = threadIdx.x >> 6;
  float4 xn[3][3], xh[3][3];
#pragma unroll
  for (int bi = 0; bi < 3; ++bi) {
    int b = b0 + bi;
#pragma unroll
    for (int jj = 0; jj < 3; ++jj) {
      int idx = lane + 64 * jj;
      float4 s = make_float4(0.f, 0.f, 0.f, 0.f);
#pragma unroll
      for (int g = 0; g < 4; ++g) {
        float4 x = ((const float4*)(neighp + ((size_t)g * BB + b) * DD))[idx];
        s.x += x.x; s.y += x.y; s.z += x.z; s.w += x.w;
      }
      xn[bi][jj] = make_float4(s.x * (1.f / 96.f), s.y * (1.f / 96.f),
                               s.z * (1.f / 96.f), s.w * (1.f / 96.f));
      xh[bi][jj] = ((const float4*)(hist + (size_t)b * HH * DD))[idx];  // h=0 row
    }
  }
  for (int i = 0; i < 8; ++i) {
    int e = e0 + wave * 8 + i;
    const float4* wl4 = (const float4*)(Wl + (size_t)e * DD);
    const float4* wr4 = (const float4*)(Wr + (size_t)e * DD);
    float pl[3] = {0.f, 0.f, 0.f}, pr[3] = {0.f, 0.f, 0.f};
#pragma unroll
    for (int jj = 0; jj < 3; ++jj) {
      float4 wl = wl4[lane + 64 * jj];
      float4 wr = wr4[lane + 64 * jj];
#pragma unroll
      for (int bi = 0; bi < 3; ++bi) {
        pl[bi] += dot4(wl, xn[bi][jj]);
        pr[bi] += dot4(wr, xh[bi][jj]);
      }
    }
#pragma unroll
    for (int bi = 0; bi < 3; ++bi) {
      float pp = pl[bi], qq = pr[bi];
      for (int off = 32; off; off >>= 1) {
        pp += __shfl_down(pp, off, 64);
        qq += __shfl_down(qq, off, 64);
      }
      if (lane == 0) {
        float nle = pp + bl[e];
        nl[(size_t)(b0 + bi) * DD + e] = nle;
        u0[(size_t)(b0 + bi) * DD + e] = qq + nle;
      }
    }
  }
}

// ---------------------------------------------------------------------------
// D3 k_q (448 blocks flat):
//   [0,256)   : Q[b,a] = u0[b,:]·W_Q[a,:] + b_Q[a]
//   [256,448) : MT = MTp[0]+MTp[1]+MTp[2]+MTp[3]  (float4 elementwise)
// ---------------------------------------------------------------------------
__global__ void __launch_bounds__(256)
k_q(const float* __restrict__ u0, const float* __restrict__ WQ,
    const float* __restrict__ bQ, const float* __restrict__ MTp,
    float* __restrict__ Qm, float* __restrict__ MT) {
  int bid = blockIdx.x, tid = threadIdx.x;
  if (bid < 256) {
    int a0 = (bid & 7) * 32;
    int b0 = (bid >> 3) * 3;
    int lane = tid & 63, wave = tid >> 6;
    float4 x[3][3];
#pragma unroll
    for (int bi = 0; bi < 3; ++bi)
#pragma unroll
      for (int jj = 0; jj < 3; ++jj)
        x[bi][jj] = ((const float4*)(u0 + (size_t)(b0 + bi) * DD))[lane + 64 * jj];
    for (int i = 0; i < 8; ++i) {
      int a = a0 + wave * 8 + i;
      const float4* w4 = (const float4*)(WQ + (size_t)a * DD);
      float p[3] = {0.f, 0.f, 0.f};
#pragma unroll
      for (int jj = 0; jj < 3; ++jj) {
        float4 w = w4[lane + 64 * jj];
#pragma unroll
        for (int bi = 0; bi < 3; ++bi) p[bi] += dot4(w, x[bi][jj]);
      }
#pragma unroll
      for (int bi = 0; bi < 3; ++bi) {
        float pp = p[bi];
        for (int off = 32; off; off >>= 1) pp += __shfl_down(pp, off, 64);
        if (lane == 0) Qm[(size_t)(b0 + bi) * AA + a] = pp + bQ[a];
      }
    }
  } else {
    int i4 = (bid - 256) * 256 + tid;  // float4 index, 192*256 = 49152 total
    const float4* p = (const float4*)MTp;
    float4 a = p[i4], b = p[WSLAB4 + i4], c = p[2 * WSLAB4 + i4], d = p[3 * WSLAB4 + i4];
    ((float4*)MT)[i4] = make_float4(a.x + b.x + c.x + d.x, a.y + b.y + c.y + d.y,
                                    a.z + b.z + c.z + d.z, a.w + b.w + c.w + d.w);
  }
}

// ---------------------------------------------------------------------------
// D4 k_v: v[b,d] = (1/16) * Q[b,:]·MT[d,:]   grid (24, 32)   (K = 256)
// ---------------------------------------------------------------------------
__global__ void k_v(const float* __restrict__ Qm, const float* __restrict__ MT,
                    float* __restrict__ vv) {
  int d0 = blockIdx.x * 32;
  int b0 = blockIdx.y * 3;
  int lane = threadIdx.x & 63, wave = threadIdx.x >> 6;
  float4 x[3];
#pragma unroll
  for (int bi = 0; bi < 3; ++bi)
    x[bi] = ((const float4*)(Qm + (size_t)(b0 + bi) * AA))[lane];
  for (int i = 0; i < 8; ++i) {
    int d = d0 + wave * 8 + i;
    float4 w = ((const float4*)(MT + (size_t)d * AA))[lane];
    float p[3];
#pragma unroll
    for (int bi = 0; bi < 3; ++bi) p[bi] = dot4(w, x[bi]);
#pragma unroll
    for (int bi = 0; bi < 3; ++bi) {
      float pp = p[bi];
      for (int off = 32; off; off >>= 1) pp += __shfl_down(pp, off, 64);
      if (lane == 0) vv[(size_t)(b0 + bi) * DD + d] = pp * (1.f / 16.f);
    }
  }
}

// ---------------------------------------------------------------------------
// D5 k_scores: scores[b,h] = hist[b,h,:]·v[b,:]   grid (96, 5), 20 h/block
// ---------------------------------------------------------------------------
__global__ void k_scores(const float* __restrict__ hist, const float* __restrict__ vv,
                         float* __restrict__ sc) {
  int b = blockIdx.x, hg = blockIdx.y;
  int lane = threadIdx.x & 63, wave = threadIdx.x >> 6;
  float4 v[3];
  const float4* vb = (const float4*)(vv + (size_t)b * DD);
#pragma unroll
  for (int jj = 0; jj < 3; ++jj) v[jj] = vb[lane + 64 * jj];
  const float* hb = hist + (size_t)b * HH * DD;
  for (int i = 0; i < 5; ++i) {
    int h = hg * 20 + wave * 5 + i;
    const float4* r = (const float4*)(hb + (size_t)h * DD);
    float p = 0.f;
#pragma unroll
    for (int jj = 0; jj < 3; ++jj) p += dot4(r[lane + 64 * jj], v[jj]);
    for (int off = 32; off; off >>= 1) p += __shfl_down(p, off, 64);
    if (lane == 0) sc[b * 128 + h] = p;
  }
}

// ---------------------------------------------------------------------------
// D6 k_wsum: softmax (wave 0, per block) + weighted hist sum.
// HIGH-TLP shape: grid (96, 12), 64 e per block, 4 h-groups x 25 h/thread,
// LDS 4-way reduce. 1152 blocks -> ~18 waves/CU of latency hiding.
// ---------------------------------------------------------------------------
__global__ void __launch_bounds__(256)
k_wsum(const float* __restrict__ hist, const float* __restrict__ sc,
       float* __restrict__ wsum) {
  int b = blockIdx.x;
  int es = blockIdx.y;                 // 64-col slice
  int tid = threadIdx.x, lane = tid & 63, wave = tid >> 6;
  __shared__ float sal[HH];
  __shared__ float psum[4][64];
  if (tid < HH) sal[tid] = sc[b * 128 + tid];
  __syncthreads();
  if (wave == 0) {
    float x0 = (lane < HH) ? sal[lane] : -1e30f;
    float x1 = (lane + 64 < HH) ? sal[lane + 64] : -1e30f;
    float m = fmaxf(x0, x1);
    for (int off = 32; off; off >>= 1) m = fmaxf(m, __shfl_xor(m, off, 64));
    float e0 = (lane < HH) ? __expf(x0 - m) : 0.f;
    float e1 = (lane + 64 < HH) ? __expf(x1 - m) : 0.f;
    float s = e0 + e1;
    for (int off = 32; off; off >>= 1) s += __shfl_xor(s, off, 64);
    float inv = 1.f / s;
    if (lane < HH) sal[lane] = e0 * inv;
    if (lane + 64 < HH) sal[lane + 64] = e1 * inv;
  }
  __syncthreads();
  int e = es * 64 + lane;
  const float* hb = hist + (size_t)b * HH * DD + e;
  int h0 = wave * 25;
  float acc = 0.f;
#pragma unroll
  for (int i = 0; i < 25; i += 5) {  // 5 loads in flight per batch
    float v0 = hb[(size_t)(h0 + i + 0) * DD];
    float v1 = hb[(size_t)(h0 + i + 1) * DD];
    float v2 = hb[(size_t)(h0 + i + 2) * DD];
    float v3 = hb[(size_t)(h0 + i + 3) * DD];
    float v4 = hb[(size_t)(h0 + i + 4) * DD];
    acc += sal[h0 + i + 0] * v0 + sal[h0 + i + 1] * v1 + sal[h0 + i + 2] * v2 +
           sal[h0 + i + 3] * v3 + sal[h0 + i + 4] * v4;
  }
  psum[wave][lane] = acc;
  __syncthreads();
  if (tid < 64) {
    float s = psum[0][tid] + psum[1][tid] + psum[2][tid] + psum[3][tid];
    wsum[(size_t)b * DD + es * 64 + tid] = s;
  }
}

// ---------------------------------------------------------------------------
// D7 k_orow_write: orow[b,d] = nl[b,d] + wsum[b,:]·W_r[d,:], then broadcast
// directly to out[b, 0..127, d] (via LDS stage). grid (24, 32).
// ---------------------------------------------------------------------------
__global__ void k_orow_write(const float* __restrict__ wsum, const float* __restrict__ Wr,
                             const float* __restrict__ nl, float* __restrict__ out) {
  int d0 = blockIdx.x * 32;
  int b0 = blockIdx.y * 3;
  int lane = threadIdx.x & 63, wave = threadIdx.x >> 6;
  __shared__ __align__(16) float s_o[3][32];
  float4 x[3][3];
#pragma unroll
  for (int bi = 0; bi < 3; ++bi)
#pragma unroll
    for (int jj = 0; jj < 3; ++jj)
      x[bi][jj] = ((const float4*)(wsum + (size_t)(b0 + bi) * DD))[lane + 64 * jj];
  for (int i = 0; i < 8; ++i) {
    int d = d0 + wave * 8 + i;
    const float4* w4 = (const float4*)(Wr + (size_t)d * DD);
    float p[3] = {0.f, 0.f, 0.f};
#pragma unroll
    for (int jj = 0; jj < 3; ++jj) {
      float4 w = w4[lane + 64 * jj];
#pragma unroll
      for (int bi = 0; bi < 3; ++bi) p[bi] += dot4(w, x[bi][jj]);
    }
#pragma unroll
    for (int bi = 0; bi < 3; ++bi) {
      float pp = p[bi];
      for (int off = 32; off; off >>= 1) pp += __shfl_down(pp, off, 64);
      if (lane == 0)
        s_o[bi][wave * 8 + i] = pp + nl[(size_t)(b0 + bi) * DD + d];
    }
  }
  __syncthreads();
  float4* out4 = (float4*)out;
  int d4 = d0 >> 2;
#pragma unroll
  for (int k = 0; k < 12; ++k) {
    int g = threadIdx.x + (k << 8);
    int seg = g >> 3, off = g & 7;
    int bi = seg >> 7, n = seg & 127;
    float4 val = *(const float4*)&s_o[bi][off * 4];
    out4[((size_t)(b0 + bi) * NN + n) * (DD / 4) + d4 + off] = val;
  }
}

// ---------------------------------------------------------------------------
extern "C" void kernel_launch(void* const* d_in, const int* in_sizes, int n_in,
                              void* d_out, int out_size, void* d_ws, size_t ws_size,
                              hipStream_t stream) {
  const float *hist = nullptr, *Wl = nullptr, *Wr = nullptr, *WK = nullptr,
              *WQ = nullptr, *bl = nullptr, *bQ = nullptr;
  int seenDxD = 0, seenAxD = 0;
  for (int i = 0; i < n_in; ++i) {
    int s = in_sizes[i];
    const float* p = (const float*)d_in[i];
    if (s == BB * HH * DD) hist = p;
    else if (s == BB * NN * DD) { /* candidate — unused */ }
    else if (s == DD * DD) { if (seenDxD++ == 0) Wl = p; else Wr = p; }
    else if (s == AA * DD) { if (seenAxD++ == 0) WK = p; else WQ = p; }
    else if (s == DD) bl = p;
    else if (s == AA) bQ = p;
  }

  float* ws = (float*)d_ws;
  float* MTp    = ws + 0;         // 4 * 196608 = 786432
  float* MT     = ws + 786432;    // 196608
  float* neighp = ws + 983040;    // 4*96*768 = 294912
  float* nl     = ws + 1277952;   // 73728
  float* u0     = ws + 1351680;   // 73728
  float* Qm     = ws + 1425408;   // 24576
  float* vv     = ws + 1449984;   // 73728
  float* sc     = ws + 1523712;   // 12288
  float* wsum   = ws + 1536000;   // 73728  -> total ~6.4 MB
  float* out = (float*)d_out;

  k_prep      <<<dim3(1152),   dim3(256), 0, stream>>>(Wr, WK, hist, MTp, neighp);
  k_nl_u0     <<<dim3(24, 32), dim3(256), 0, stream>>>(neighp, hist, Wl, bl, Wr, nl, u0);
  k_q         <<<dim3(448),    dim3(256), 0, stream>>>(u0, WQ, bQ, MTp, Qm, MT);
  k_v         <<<dim3(24, 32), dim3(256), 0, stream>>>(Qm, MT, vv);
  k_scores    <<<dim3(96, 5),  dim3(256), 0, stream>>>(hist, vv, sc);
  k_wsum      <<<dim3(96, 12), dim3(256), 0, stream>>>(hist, sc, wsum);
  k_orow_write<<<dim3(24, 32), dim3(256), 0, stream>>>(wsum, Wr, nl, out);
}